// Round 2
// baseline (1635.384 us; speedup 1.0000x reference)
//
#include <hip/hip_runtime.h>
#include <hip/hip_bf16.h>
#include <math.h>

// Problem constants
#define NC 3
#define NK 64
#define KK 3
#define K2 9
#define PAD 1
#define SCALE 4
#define S2 16
#define MID 4
#define B 4
#define H 128
#define W 128
#define HW (H*W)          // 16384
#define CIN 67            // NK + NC
#define OUT_HW (H*SCALE)  // 512

__device__ __forceinline__ float fast_sigmoid(float v) { return 1.f / (1.f + __expf(-v)); }
__device__ __forceinline__ float fast_tanh(float v) { return 2.f / (1.f + __expf(-2.f * v)) - 1.f; }

// load a zero-padded 3x3 patch of one channel plane (HxW) at (y,x)
__device__ __forceinline__ void load_patch(const float* __restrict__ xc, int y, int x, float* p) {
#pragma unroll
    for (int dy = -1; dy <= 1; dy++) {
#pragma unroll
        for (int dx = -1; dx <= 1; dx++) {
            int yy = y + dy, xx = x + dx;
            float v = (yy >= 0 && yy < H && xx >= 0 && xx < W) ? xc[yy * W + xx] : 0.f;
            p[(dy + 1) * 3 + (dx + 1)] = v;
        }
    }
}

// ---------------------------------------------------------------------------
// ConvLSTM with h=0,c=0: only first NC input channels of lstm_w matter;
// f-gate irrelevant (c_prev=0). blockIdx.y selects a 16-channel gate group.
// ---------------------------------------------------------------------------
__global__ __launch_bounds__(256) void k_lstm(const float* __restrict__ X,
                                              const float* __restrict__ lw,
                                              const float* __restrict__ lb,
                                              float* __restrict__ xcatA,
                                              float* __restrict__ hid_out,
                                              float* __restrict__ cell_out) {
    int t = blockIdx.x * blockDim.x + threadIdx.x;
    int b = t >> 14, hw = t & (HW - 1), y = hw >> 7, x = hw & (W - 1);
    int nk0 = blockIdx.y * 16;
    float p[NC][9];
#pragma unroll
    for (int c = 0; c < NC; c++) load_patch(X + (b * NC + c) * HW, y, x, p[c]);
    float* xc = xcatA + (size_t)b * CIN * HW;
    for (int i = 0; i < 16; i++) {
        int nk = nk0 + i;
        float gi = lb[nk], go = lb[2 * NK + nk], gg = lb[3 * NK + nk];
#pragma unroll
        for (int c = 0; c < NC; c++) {
            const float* wi = lw + (size_t)(nk) * (CIN * 9) + c * 9;
            const float* wo = lw + (size_t)(2 * NK + nk) * (CIN * 9) + c * 9;
            const float* wg = lw + (size_t)(3 * NK + nk) * (CIN * 9) + c * 9;
#pragma unroll
            for (int tt = 0; tt < 9; tt++) {
                gi += p[c][tt] * wi[tt];
                go += p[c][tt] * wo[tt];
                gg += p[c][tt] * wg[tt];
            }
        }
        float cv = fast_sigmoid(gi) * fast_tanh(gg);
        float hv = fast_sigmoid(go) * fast_tanh(cv);
        xc[nk * HW + hw] = hv;
        hid_out[(b * NK + nk) * HW + hw] = hv;
        cell_out[(b * NK + nk) * HW + hw] = cv;
    }
}

// copy lr (X) into channels 64..66 of both xcat buffers
__global__ __launch_bounds__(256) void k_copy_lr(const float* __restrict__ X,
                                                 float* __restrict__ xcatA,
                                                 float* __restrict__ xcatB) {
    int t = blockIdx.x * blockDim.x + threadIdx.x;
    int b = t >> 14, hw = t & (HW - 1);
#pragma unroll
    for (int c = 0; c < NC; c++) {
        float v = X[(b * NC + c) * HW + hw];
        xcatA[(size_t)b * CIN * HW + (NK + c) * HW + hw] = v;
        xcatB[(size_t)b * CIN * HW + (NK + c) * HW + hw] = v;
    }
}

// transpose deform main weight [64][603] -> [603][64] for float4 inner loops
__global__ void k_transw(const float* __restrict__ w, float* __restrict__ wT) {
    int i = blockIdx.x * blockDim.x + threadIdx.x;
    if (i < NK * CIN * K2) {
        int o = i / (CIN * K2), ck = i % (CIN * K2);
        wT[ck * NK + o] = w[i];
    }
}

// ---------------------------------------------------------------------------
// Offset + mask convs for one deform layer. blockIdx.y: 0 -> off rows 0..8,
// 1 -> off rows 9..17, 2 -> mask (2*sigmoid).
// ---------------------------------------------------------------------------
__global__ __launch_bounds__(256) void k_offmask(const float* __restrict__ xcat,
                                                 const float* __restrict__ ow,
                                                 const float* __restrict__ ob,
                                                 const float* __restrict__ mw,
                                                 const float* __restrict__ mb,
                                                 float* __restrict__ offb,
                                                 float* __restrict__ maskb) {
    int t = blockIdx.x * blockDim.x + threadIdx.x;
    int b = t >> 14, hw = t & (HW - 1), y = hw >> 7, x = hw & (W - 1);
    int g = blockIdx.y;
    const float* wbase = (g == 2) ? mw : (ow + (size_t)(g * 9) * (CIN * 9));
    const float* bbase = (g == 2) ? mb : (ob + g * 9);
    float acc[9];
#pragma unroll
    for (int i = 0; i < 9; i++) acc[i] = bbase[i];
    const float* xb = xcat + (size_t)b * CIN * HW;
    for (int c = 0; c < CIN; c++) {
        float p[9];
        load_patch(xb + c * HW, y, x, p);
#pragma unroll
        for (int oc = 0; oc < 9; oc++) {
            const float* w = wbase + (size_t)oc * (CIN * 9) + c * 9;
#pragma unroll
            for (int tt = 0; tt < 9; tt++) acc[oc] += p[tt] * w[tt];
        }
    }
    if (g == 2) {
#pragma unroll
        for (int oc = 0; oc < 9; oc++) maskb[(b * 9 + oc) * HW + hw] = 2.f * fast_sigmoid(acc[oc]);
    } else {
#pragma unroll
        for (int oc = 0; oc < 9; oc++) offb[(b * 18 + g * 9 + oc) * HW + hw] = acc[oc];
    }
}

// ---------------------------------------------------------------------------
// Deformable gather + einsum. blockIdx.y selects a 16-output-channel group.
// Per thread: 9 taps' bilinear setup, per channel gather one value then 16
// FMAs against wT (contiguous float4, wave-uniform -> broadcast).
// ---------------------------------------------------------------------------
__global__ __launch_bounds__(256) void k_deform(const float* __restrict__ xcat,
                                                const float* __restrict__ offb,
                                                const float* __restrict__ maskb,
                                                const float* __restrict__ wT,
                                                const float* __restrict__ bias,
                                                float* __restrict__ xout) {
    int t = blockIdx.x * blockDim.x + threadIdx.x;
    int b = t >> 14, hw = t & (HW - 1), y = hw >> 7, x = hw & (W - 1);
    int og = blockIdx.y * 16;
    float2 acc2[8];
#pragma unroll
    for (int i = 0; i < 8; i++) acc2[i] = make_float2(0.f, 0.f);

    // per-tap bilinear setup (hoisted)
    float w00[K2], w01[K2], w10[K2], w11[K2];
    int i00[K2], i01[K2], i10[K2], i11[K2];
#pragma unroll
    for (int k = 0; k < K2; k++) {
        int ky = k / 3, kx = k % 3;
        float offy = offb[(b * 18 + 2 * k) * HW + hw];
        float offx = offb[(b * 18 + 2 * k + 1) * HW + hw];
        float m = maskb[(b * 9 + k) * HW + hw];
        float py = (float)(y + ky - 1) + offy;
        float px = (float)(x + kx - 1) + offx;
        float fy = floorf(py), fx = floorf(px);
        float wy = py - fy, wx = px - fx;
        int y0 = (int)fy, x0 = (int)fx;
        int y1 = y0 + 1, x1 = x0 + 1;
        float vy0 = (y0 >= 0 && y0 <= H - 1) ? 1.f : 0.f;
        float vy1 = (y1 >= 0 && y1 <= H - 1) ? 1.f : 0.f;
        float vx0 = (x0 >= 0 && x0 <= W - 1) ? 1.f : 0.f;
        float vx1 = (x1 >= 0 && x1 <= W - 1) ? 1.f : 0.f;
        int yc0 = min(max(y0, 0), H - 1), yc1 = min(max(y1, 0), H - 1);
        int xc0 = min(max(x0, 0), W - 1), xc1 = min(max(x1, 0), W - 1);
        w00[k] = (1.f - wy) * (1.f - wx) * m * vy0 * vx0;
        w01[k] = (1.f - wy) * wx * m * vy0 * vx1;
        w10[k] = wy * (1.f - wx) * m * vy1 * vx0;
        w11[k] = wy * wx * m * vy1 * vx1;
        i00[k] = yc0 * W + xc0; i01[k] = yc0 * W + xc1;
        i10[k] = yc1 * W + xc0; i11[k] = yc1 * W + xc1;
    }

    const float* xb = xcat + (size_t)b * CIN * HW;
#pragma unroll 1
    for (int k = 0; k < K2; k++) {
        float a00 = w00[k], a01 = w01[k], a10 = w10[k], a11 = w11[k];
        int j00 = i00[k], j01 = i01[k], j10 = i10[k], j11 = i11[k];
        const float* wk = wT + (size_t)k * NK + og;
        for (int c = 0; c < CIN; c++) {
            const float* xc = xb + c * HW;
            float v = a00 * xc[j00] + a01 * xc[j01] + a10 * xc[j10] + a11 * xc[j11];
            const float4* wv = (const float4*)(wk + (size_t)c * (K2 * NK));
#pragma unroll
            for (int q = 0; q < 4; q++) {
                float4 wq = wv[q];
                acc2[2 * q + 0].x += v * wq.x;
                acc2[2 * q + 0].y += v * wq.y;
                acc2[2 * q + 1].x += v * wq.z;
                acc2[2 * q + 1].y += v * wq.w;
            }
        }
    }
    float* xo = xout + (size_t)b * CIN * HW;
#pragma unroll
    for (int q = 0; q < 8; q++) {
        xo[(og + 2 * q + 0) * HW + hw] = acc2[q].x + bias[og + 2 * q + 0];
        xo[(og + 2 * q + 1) * HW + hw] = acc2[q].y + bias[og + 2 * q + 1];
    }
}

// final 3-channel conv over 67-channel concat; blockIdx.y = output channel
__global__ __launch_bounds__(256) void k_conv3(const float* __restrict__ xcat,
                                               const float* __restrict__ cw,
                                               const float* __restrict__ cb,
                                               float* __restrict__ y3) {
    int t = blockIdx.x * blockDim.x + threadIdx.x;
    int b = t >> 14, hw = t & (HW - 1), y = hw >> 7, x = hw & (W - 1);
    int oc = blockIdx.y;
    float acc = cb[oc];
    const float* xb = xcat + (size_t)b * CIN * HW;
    const float* wb = cw + (size_t)oc * (CIN * 9);
    for (int c = 0; c < CIN; c++) {
        float p[9];
        load_patch(xb + c * HW, y, x, p);
        const float* w = wb + c * 9;
#pragma unroll
        for (int tt = 0; tt < 9; tt++) acc += p[tt] * w[tt];
    }
    y3[(b * NC + oc) * HW + hw] = acc;
}

// global average pool: one block per (b,c)
__global__ __launch_bounds__(256) void k_pool(const float* __restrict__ y3,
                                              float* __restrict__ pooled) {
    int bc = blockIdx.x;  // 0..11
    const float* p = y3 + (size_t)bc * HW;
    float s = 0.f;
    for (int i = threadIdx.x; i < HW; i += 256) s += p[i];
    __shared__ float red[256];
    red[threadIdx.x] = s;
    __syncthreads();
    for (int off = 128; off > 0; off >>= 1) {
        if (threadIdx.x < off) red[threadIdx.x] += red[threadIdx.x + off];
        __syncthreads();
    }
    if (threadIdx.x == 0) pooled[bc] = red[0] / (float)HW;
}

// tiny per-branch channel MLP -> ch[b,s,c,k]
__global__ void k_ch(const float* __restrict__ pooled, const float* __restrict__ w1,
                     const float* __restrict__ b1, const float* __restrict__ w2,
                     const float* __restrict__ b2, float* __restrict__ chbuf) {
    int t = threadIdx.x;
    if (t >= B * S2) return;
    int b = t >> 4, s = t & 15;
    float h1[MID];
#pragma unroll
    for (int m = 0; m < MID; m++) {
        float a = b1[s * MID + m];
#pragma unroll
        for (int c = 0; c < NC; c++) a += pooled[b * NC + c] * w1[(s * MID + m) * NC + c];
        h1[m] = fmaxf(a, 0.f);
    }
    for (int kk = 0; kk < NC * K2; kk++) {
        float a = b2[s * (NC * K2) + kk];
#pragma unroll
        for (int m = 0; m < MID; m++) a += h1[m] * w2[(s * (NC * K2) + kk) * MID + m];
        chbuf[(b * S2 + s) * (NC * K2) + kk] = a;
    }
}

// ---------------------------------------------------------------------------
// Fused DDF upsample: spatial-filter conv + dynamic combine + pixel_shuffle
// + clip. blockIdx.y selects 4 of the 16 branches; that quarter of sp_w/sp_b
// and ch staged in LDS (block is single-batch).
// ---------------------------------------------------------------------------
__global__ __launch_bounds__(256) void k_ddf(const float* __restrict__ y3,
                                             const float* __restrict__ spw,
                                             const float* __restrict__ spb,
                                             const float* __restrict__ chbuf,
                                             float* __restrict__ out) {
    __shared__ float s_spw[4 * K2 * NC * 9];  // 972
    __shared__ float s_spb[4 * K2];           // 36
    __shared__ float s_ch[4 * NC * K2];       // 108
    int t = blockIdx.x * blockDim.x + threadIdx.x;
    int b = t >> 14, hw = t & (HW - 1), y = hw >> 7, x = hw & (W - 1);
    int s0 = blockIdx.y * 4;
    for (int i = threadIdx.x; i < 4 * K2 * NC * 9; i += 256) s_spw[i] = spw[s0 * K2 * NC * 9 + i];
    if (threadIdx.x < 4 * K2) s_spb[threadIdx.x] = spb[s0 * K2 + threadIdx.x];
    if (threadIdx.x < 4 * NC * K2) s_ch[threadIdx.x] = chbuf[b * (S2 * NC * K2) + s0 * NC * K2 + threadIdx.x];
    __syncthreads();
    float p[NC][9];
#pragma unroll
    for (int c = 0; c < NC; c++) load_patch(y3 + (b * NC + c) * HW, y, x, p[c]);
#pragma unroll
    for (int si = 0; si < 4; si++) {
        int s = s0 + si;
        float spv[K2];
#pragma unroll
        for (int k = 0; k < K2; k++) {
            float a = s_spb[si * K2 + k];
            const float* w = s_spw + (si * K2 + k) * (NC * 9);
#pragma unroll
            for (int c = 0; c < NC; c++)
#pragma unroll
                for (int tt = 0; tt < 9; tt++) a += p[c][tt] * w[c * 9 + tt];
            spv[k] = a;
        }
        int sy = s >> 2, sx = s & 3;
#pragma unroll
        for (int c = 0; c < NC; c++) {
            float a = 0.f;
            const float* chp = s_ch + (si * NC + c) * K2;
#pragma unroll
            for (int k = 0; k < K2; k++) a += p[c][k] * (chp[k] + spv[k]);
            a = fminf(fmaxf(a, 0.f), 255.f);
            out[((size_t)(b * NC + c) * OUT_HW + (y * SCALE + sy)) * OUT_HW + (x * SCALE + sx)] = a;
        }
    }
}

extern "C" void kernel_launch(void* const* d_in, const int* in_sizes, int n_in,
                              void* d_out, int out_size, void* d_ws, size_t ws_size,
                              hipStream_t stream) {
    const float* X = (const float*)d_in[0];
    const float* lstm_w = (const float*)d_in[1];
    const float* lstm_b = (const float*)d_in[2];
    const float* ow[3] = {(const float*)d_in[3], (const float*)d_in[9], (const float*)d_in[15]};
    const float* ob[3] = {(const float*)d_in[4], (const float*)d_in[10], (const float*)d_in[16]};
    const float* mw[3] = {(const float*)d_in[5], (const float*)d_in[11], (const float*)d_in[17]};
    const float* mb[3] = {(const float*)d_in[6], (const float*)d_in[12], (const float*)d_in[18]};
    const float* dw[3] = {(const float*)d_in[7], (const float*)d_in[13], (const float*)d_in[19]};
    const float* db[3] = {(const float*)d_in[8], (const float*)d_in[14], (const float*)d_in[20]};
    const float* conv_w = (const float*)d_in[21];
    const float* conv_b = (const float*)d_in[22];
    const float* sp_w = (const float*)d_in[23];
    const float* sp_b = (const float*)d_in[24];
    const float* ch_w1 = (const float*)d_in[25];
    const float* ch_b1 = (const float*)d_in[26];
    const float* ch_w2 = (const float*)d_in[27];
    const float* ch_b2 = (const float*)d_in[28];

    float* out = (float*)d_out;
    const size_t OUT_IMG = (size_t)B * NC * OUT_HW * OUT_HW;  // 3145728
    const size_t HIDSZ = (size_t)B * NK * HW;                 // 4194304
    float* hid_out = out + OUT_IMG;
    float* cell_out = out + OUT_IMG + HIDSZ;

    float* ws = (float*)d_ws;
    const size_t XCAT = (size_t)B * CIN * HW;  // 4390912
    float* xcatA = ws;            ws += XCAT;
    float* xcatB = ws;            ws += XCAT;
    float* offb = ws;             ws += (size_t)B * 18 * HW;
    float* maskb = ws;            ws += (size_t)B * 9 * HW;
    float* wT[3];
    for (int i = 0; i < 3; i++) { wT[i] = ws; ws += NK * CIN * K2; }
    float* y3 = ws;               ws += (size_t)B * NC * HW;
    float* pooled = ws;           ws += 16;
    float* chbuf = ws;            ws += (size_t)B * S2 * NC * K2;

    dim3 blk(256);
    dim3 g1(B * HW / 256);        // 256 blocks
    dim3 g4(B * HW / 256, 4);
    dim3 g3(B * HW / 256, 3);

    k_lstm<<<g4, blk, 0, stream>>>(X, lstm_w, lstm_b, xcatA, hid_out, cell_out);
    k_copy_lr<<<g1, blk, 0, stream>>>(X, xcatA, xcatB);
    int ntw = NK * CIN * K2;
    for (int i = 0; i < 3; i++)
        k_transw<<<(ntw + 255) / 256, 256, 0, stream>>>(dw[i], wT[i]);

    // layer 1: xcatA -> xcatB
    k_offmask<<<g3, blk, 0, stream>>>(xcatA, ow[0], ob[0], mw[0], mb[0], offb, maskb);
    k_deform<<<g4, blk, 0, stream>>>(xcatA, offb, maskb, wT[0], db[0], xcatB);
    // layer 2: xcatB -> xcatA
    k_offmask<<<g3, blk, 0, stream>>>(xcatB, ow[1], ob[1], mw[1], mb[1], offb, maskb);
    k_deform<<<g4, blk, 0, stream>>>(xcatB, offb, maskb, wT[1], db[1], xcatA);
    // layer 3: xcatA -> xcatB
    k_offmask<<<g3, blk, 0, stream>>>(xcatA, ow[2], ob[2], mw[2], mb[2], offb, maskb);
    k_deform<<<g4, blk, 0, stream>>>(xcatA, offb, maskb, wT[2], db[2], xcatB);

    k_conv3<<<g3, blk, 0, stream>>>(xcatB, conv_w, conv_b, y3);
    k_pool<<<dim3(B * NC), blk, 0, stream>>>(y3, pooled);
    k_ch<<<dim3(1), dim3(64), 0, stream>>>(pooled, ch_w1, ch_b1, ch_w2, ch_b2, chbuf);
    k_ddf<<<g4, blk, 0, stream>>>(y3, sp_w, sp_b, chbuf, out);
}

// Round 3
// 874.264 us; speedup vs baseline: 1.8706x; 1.8706x over previous
//
#include <hip/hip_runtime.h>
#include <hip/hip_bf16.h>
#include <math.h>

// Problem constants
#define NC 3
#define NK 64
#define KK 3
#define K2 9
#define PAD 1
#define SCALE 4
#define S2 16
#define MID 4
#define B 4
#define H 128
#define W 128
#define HW (H*W)          // 16384
#define CIN 67            // NK + NC
#define OUT_HW (H*SCALE)  // 512

__device__ __forceinline__ float fast_sigmoid(float v) { return 1.f / (1.f + __expf(-v)); }
__device__ __forceinline__ float fast_tanh(float v) { return 2.f / (1.f + __expf(-2.f * v)) - 1.f; }

// load a zero-padded 3x3 patch of one channel plane (HxW) at (y,x)
__device__ __forceinline__ void load_patch(const float* __restrict__ xc, int y, int x, float* p) {
#pragma unroll
    for (int dy = -1; dy <= 1; dy++) {
#pragma unroll
        for (int dx = -1; dx <= 1; dx++) {
            int yy = y + dy, xx = x + dx;
            float v = (yy >= 0 && yy < H && xx >= 0 && xx < W) ? xc[yy * W + xx] : 0.f;
            p[(dy + 1) * 3 + (dx + 1)] = v;
        }
    }
}

// ---------------------------------------------------------------------------
// ConvLSTM with h=0,c=0: only first NC input channels of lstm_w matter;
// f-gate irrelevant (c_prev=0). blockIdx.y selects a 16-channel gate group.
// ---------------------------------------------------------------------------
__global__ __launch_bounds__(256) void k_lstm(const float* __restrict__ X,
                                              const float* __restrict__ lw,
                                              const float* __restrict__ lb,
                                              float* __restrict__ xcatA,
                                              float* __restrict__ hid_out,
                                              float* __restrict__ cell_out) {
    int t = blockIdx.x * blockDim.x + threadIdx.x;
    int b = t >> 14, hw = t & (HW - 1), y = hw >> 7, x = hw & (W - 1);
    int nk0 = blockIdx.y * 16;
    float p[NC][9];
#pragma unroll
    for (int c = 0; c < NC; c++) load_patch(X + (b * NC + c) * HW, y, x, p[c]);
    float* xc = xcatA + (size_t)b * CIN * HW;
    for (int i = 0; i < 16; i++) {
        int nk = nk0 + i;
        float gi = lb[nk], go = lb[2 * NK + nk], gg = lb[3 * NK + nk];
#pragma unroll
        for (int c = 0; c < NC; c++) {
            const float* wi = lw + (size_t)(nk) * (CIN * 9) + c * 9;
            const float* wo = lw + (size_t)(2 * NK + nk) * (CIN * 9) + c * 9;
            const float* wg = lw + (size_t)(3 * NK + nk) * (CIN * 9) + c * 9;
#pragma unroll
            for (int tt = 0; tt < 9; tt++) {
                gi += p[c][tt] * wi[tt];
                go += p[c][tt] * wo[tt];
                gg += p[c][tt] * wg[tt];
            }
        }
        float cv = fast_sigmoid(gi) * fast_tanh(gg);
        float hv = fast_sigmoid(go) * fast_tanh(cv);
        xc[nk * HW + hw] = hv;
        hid_out[(b * NK + nk) * HW + hw] = hv;
        cell_out[(b * NK + nk) * HW + hw] = cv;
    }
}

// copy lr (X) into channels 64..66 of both xcat buffers
__global__ __launch_bounds__(256) void k_copy_lr(const float* __restrict__ X,
                                                 float* __restrict__ xcatA,
                                                 float* __restrict__ xcatB) {
    int t = blockIdx.x * blockDim.x + threadIdx.x;
    int b = t >> 14, hw = t & (HW - 1);
#pragma unroll
    for (int c = 0; c < NC; c++) {
        float v = X[(b * NC + c) * HW + hw];
        xcatA[(size_t)b * CIN * HW + (NK + c) * HW + hw] = v;
        xcatB[(size_t)b * CIN * HW + (NK + c) * HW + hw] = v;
    }
}

// transpose deform main weight w[o][c][k] (o<64, c<67, k<9) -> wT[k][c][o]
__global__ void k_transw(const float* __restrict__ w, float* __restrict__ wT) {
    int i = blockIdx.x * blockDim.x + threadIdx.x;
    if (i < NK * CIN * K2) {
        int o = i / (CIN * K2), r = i % (CIN * K2);
        int c = r / K2, k = r % K2;
        wT[((size_t)k * CIN + c) * NK + o] = w[i];
    }
}

// ---------------------------------------------------------------------------
// Offset + mask convs for one deform layer. blockIdx.y: 0 -> off rows 0..8,
// 1 -> off rows 9..17, 2 -> mask (2*sigmoid).
// ---------------------------------------------------------------------------
__global__ __launch_bounds__(256) void k_offmask(const float* __restrict__ xcat,
                                                 const float* __restrict__ ow,
                                                 const float* __restrict__ ob,
                                                 const float* __restrict__ mw,
                                                 const float* __restrict__ mb,
                                                 float* __restrict__ offb,
                                                 float* __restrict__ maskb) {
    int t = blockIdx.x * blockDim.x + threadIdx.x;
    int b = t >> 14, hw = t & (HW - 1), y = hw >> 7, x = hw & (W - 1);
    int g = blockIdx.y;
    const float* wbase = (g == 2) ? mw : (ow + (size_t)(g * 9) * (CIN * 9));
    const float* bbase = (g == 2) ? mb : (ob + g * 9);
    float acc[9];
#pragma unroll
    for (int i = 0; i < 9; i++) acc[i] = bbase[i];
    const float* xb = xcat + (size_t)b * CIN * HW;
    for (int c = 0; c < CIN; c++) {
        float p[9];
        load_patch(xb + c * HW, y, x, p);
#pragma unroll
        for (int oc = 0; oc < 9; oc++) {
            const float* w = wbase + (size_t)oc * (CIN * 9) + c * 9;
#pragma unroll
            for (int tt = 0; tt < 9; tt++) acc[oc] += p[tt] * w[tt];
        }
    }
    if (g == 2) {
#pragma unroll
        for (int oc = 0; oc < 9; oc++) maskb[(b * 9 + oc) * HW + hw] = 2.f * fast_sigmoid(acc[oc]);
    } else {
#pragma unroll
        for (int oc = 0; oc < 9; oc++) offb[(b * 18 + g * 9 + oc) * HW + hw] = acc[oc];
    }
}

// ---------------------------------------------------------------------------
// Deformable gather + einsum, tap-split. Block = 256 threads = 64 pixels;
// the 4 waves partition the 9 taps {0-2},{3-4},{5-6},{7-8}. Each wave keeps
// all 64 output accumulators in VGPRs (per-c: <=3*4 gathers + <=3*64 FMAs,
// no gather duplication). Partials combined via LDS, bias added, written out.
// wT layout: [k][c][o] so each wave streams a contiguous wave-uniform slice.
// ---------------------------------------------------------------------------
__global__ __launch_bounds__(256, 4) void k_deform(const float* __restrict__ xcat,
                                                   const float* __restrict__ offb,
                                                   const float* __restrict__ maskb,
                                                   const float* __restrict__ wT,
                                                   const float* __restrict__ bias,
                                                   float* __restrict__ xout) {
    __shared__ float red[4 * 16 * 64];  // 16 KB
    int lane = threadIdx.x & 63;
    int wid = __builtin_amdgcn_readfirstlane((int)(threadIdx.x >> 6));
    const int TS[5] = {0, 3, 5, 7, 9};
    int ts = TS[wid], te = TS[wid + 1], nt = te - ts;

    int blk = blockIdx.x;            // 0..1023
    int b = blk >> 8;                // 4 batches * 256 blocks
    int hwbase = (blk & 255) * 64;
    int hw = hwbase + lane;
    int y = hw >> 7, x = hw & (W - 1);

    float acc[NK];
#pragma unroll
    for (int o = 0; o < NK; o++) acc[o] = 0.f;

    // bilinear setup for this wave's taps
    float w00[3], w01[3], w10[3], w11[3];
    int i00[3], i01[3], i10[3], i11[3];
    for (int j = 0; j < nt; j++) {
        int k = ts + j;
        int ky = k / 3, kx = k % 3;
        float offy = offb[(b * 18 + 2 * k) * HW + hw];
        float offx = offb[(b * 18 + 2 * k + 1) * HW + hw];
        float m = maskb[(b * 9 + k) * HW + hw];
        float py = (float)(y + ky - 1) + offy;
        float px = (float)(x + kx - 1) + offx;
        float fy = floorf(py), fx = floorf(px);
        float wy = py - fy, wx = px - fx;
        int y0 = (int)fy, x0 = (int)fx;
        int y1 = y0 + 1, x1 = x0 + 1;
        float vy0 = (y0 >= 0 && y0 <= H - 1) ? 1.f : 0.f;
        float vy1 = (y1 >= 0 && y1 <= H - 1) ? 1.f : 0.f;
        float vx0 = (x0 >= 0 && x0 <= W - 1) ? 1.f : 0.f;
        float vx1 = (x1 >= 0 && x1 <= W - 1) ? 1.f : 0.f;
        int yc0 = min(max(y0, 0), H - 1), yc1 = min(max(y1, 0), H - 1);
        int xc0 = min(max(x0, 0), W - 1), xc1 = min(max(x1, 0), W - 1);
        w00[j] = (1.f - wy) * (1.f - wx) * m * vy0 * vx0;
        w01[j] = (1.f - wy) * wx * m * vy0 * vx1;
        w10[j] = wy * (1.f - wx) * m * vy1 * vx0;
        w11[j] = wy * wx * m * vy1 * vx1;
        i00[j] = yc0 * W + xc0; i01[j] = yc0 * W + xc1;
        i10[j] = yc1 * W + xc0; i11[j] = yc1 * W + xc1;
    }

    const float* xb = xcat + (size_t)b * CIN * HW;
#pragma unroll 1
    for (int j = 0; j < nt; j++) {
        float a00 = w00[j], a01 = w01[j], a10 = w10[j], a11 = w11[j];
        int j00 = i00[j], j01 = i01[j], j10 = i10[j], j11 = i11[j];
        const float* wk = wT + (size_t)(ts + j) * CIN * NK;
        for (int c = 0; c < CIN; c++) {
            const float* xc = xb + c * HW;
            float v = a00 * xc[j00] + a01 * xc[j01] + a10 * xc[j10] + a11 * xc[j11];
            const float4* wv4 = (const float4*)(wk + (size_t)c * NK);
#pragma unroll
            for (int q = 0; q < 16; q++) {
                float4 wq = wv4[q];
                acc[4 * q + 0] += v * wq.x;
                acc[4 * q + 1] += v * wq.y;
                acc[4 * q + 2] += v * wq.z;
                acc[4 * q + 3] += v * wq.w;
            }
        }
    }

    // LDS reduction across the 4 waves, 16 output channels at a time
    float* xo = xout + (size_t)b * CIN * HW + hwbase;
    int px = threadIdx.x & 63, jj = threadIdx.x >> 6;
#pragma unroll 1
    for (int chunk = 0; chunk < 4; chunk++) {
#pragma unroll
        for (int j = 0; j < 16; j++) red[(wid * 16 + j) * 64 + lane] = acc[chunk * 16 + j];
        __syncthreads();
#pragma unroll
        for (int i = 0; i < 4; i++) {
            int j = jj + 4 * i;
            float s = red[(0 * 16 + j) * 64 + px] + red[(1 * 16 + j) * 64 + px]
                    + red[(2 * 16 + j) * 64 + px] + red[(3 * 16 + j) * 64 + px];
            int oc = chunk * 16 + j;
            xo[oc * HW + px] = s + bias[oc];
        }
        __syncthreads();
    }
}

// final 3-channel conv over 67-channel concat; blockIdx.y = output channel
__global__ __launch_bounds__(256) void k_conv3(const float* __restrict__ xcat,
                                               const float* __restrict__ cw,
                                               const float* __restrict__ cb,
                                               float* __restrict__ y3) {
    int t = blockIdx.x * blockDim.x + threadIdx.x;
    int b = t >> 14, hw = t & (HW - 1), y = hw >> 7, x = hw & (W - 1);
    int oc = blockIdx.y;
    float acc = cb[oc];
    const float* xb = xcat + (size_t)b * CIN * HW;
    const float* wb = cw + (size_t)oc * (CIN * 9);
    for (int c = 0; c < CIN; c++) {
        float p[9];
        load_patch(xb + c * HW, y, x, p);
        const float* w = wb + c * 9;
#pragma unroll
        for (int tt = 0; tt < 9; tt++) acc += p[tt] * w[tt];
    }
    y3[(b * NC + oc) * HW + hw] = acc;
}

// global average pool: one block per (b,c)
__global__ __launch_bounds__(256) void k_pool(const float* __restrict__ y3,
                                              float* __restrict__ pooled) {
    int bc = blockIdx.x;  // 0..11
    const float* p = y3 + (size_t)bc * HW;
    float s = 0.f;
    for (int i = threadIdx.x; i < HW; i += 256) s += p[i];
    __shared__ float red[256];
    red[threadIdx.x] = s;
    __syncthreads();
    for (int off = 128; off > 0; off >>= 1) {
        if (threadIdx.x < off) red[threadIdx.x] += red[threadIdx.x + off];
        __syncthreads();
    }
    if (threadIdx.x == 0) pooled[bc] = red[0] / (float)HW;
}

// tiny per-branch channel MLP -> ch[b,s,c,k]
__global__ void k_ch(const float* __restrict__ pooled, const float* __restrict__ w1,
                     const float* __restrict__ b1, const float* __restrict__ w2,
                     const float* __restrict__ b2, float* __restrict__ chbuf) {
    int t = threadIdx.x;
    if (t >= B * S2) return;
    int b = t >> 4, s = t & 15;
    float h1[MID];
#pragma unroll
    for (int m = 0; m < MID; m++) {
        float a = b1[s * MID + m];
#pragma unroll
        for (int c = 0; c < NC; c++) a += pooled[b * NC + c] * w1[(s * MID + m) * NC + c];
        h1[m] = fmaxf(a, 0.f);
    }
    for (int kk = 0; kk < NC * K2; kk++) {
        float a = b2[s * (NC * K2) + kk];
#pragma unroll
        for (int m = 0; m < MID; m++) a += h1[m] * w2[(s * (NC * K2) + kk) * MID + m];
        chbuf[(b * S2 + s) * (NC * K2) + kk] = a;
    }
}

// ---------------------------------------------------------------------------
// Fused DDF upsample: spatial-filter conv + dynamic combine + pixel_shuffle
// + clip. blockIdx.y selects 4 of the 16 branches; that quarter of sp_w/sp_b
// and ch staged in LDS (block is single-batch).
// ---------------------------------------------------------------------------
__global__ __launch_bounds__(256) void k_ddf(const float* __restrict__ y3,
                                             const float* __restrict__ spw,
                                             const float* __restrict__ spb,
                                             const float* __restrict__ chbuf,
                                             float* __restrict__ out) {
    __shared__ float s_spw[4 * K2 * NC * 9];  // 972
    __shared__ float s_spb[4 * K2];           // 36
    __shared__ float s_ch[4 * NC * K2];       // 108
    int t = blockIdx.x * blockDim.x + threadIdx.x;
    int b = t >> 14, hw = t & (HW - 1), y = hw >> 7, x = hw & (W - 1);
    int s0 = blockIdx.y * 4;
    for (int i = threadIdx.x; i < 4 * K2 * NC * 9; i += 256) s_spw[i] = spw[s0 * K2 * NC * 9 + i];
    if (threadIdx.x < 4 * K2) s_spb[threadIdx.x] = spb[s0 * K2 + threadIdx.x];
    if (threadIdx.x < 4 * NC * K2) s_ch[threadIdx.x] = chbuf[b * (S2 * NC * K2) + s0 * NC * K2 + threadIdx.x];
    __syncthreads();
    float p[NC][9];
#pragma unroll
    for (int c = 0; c < NC; c++) load_patch(y3 + (b * NC + c) * HW, y, x, p[c]);
#pragma unroll
    for (int si = 0; si < 4; si++) {
        int s = s0 + si;
        float spv[K2];
#pragma unroll
        for (int k = 0; k < K2; k++) {
            float a = s_spb[si * K2 + k];
            const float* w = s_spw + (si * K2 + k) * (NC * 9);
#pragma unroll
            for (int c = 0; c < NC; c++)
#pragma unroll
                for (int tt = 0; tt < 9; tt++) a += p[c][tt] * w[c * 9 + tt];
            spv[k] = a;
        }
        int sy = s >> 2, sx = s & 3;
#pragma unroll
        for (int c = 0; c < NC; c++) {
            float a = 0.f;
            const float* chp = s_ch + (si * NC + c) * K2;
#pragma unroll
            for (int k = 0; k < K2; k++) a += p[c][k] * (chp[k] + spv[k]);
            a = fminf(fmaxf(a, 0.f), 255.f);
            out[((size_t)(b * NC + c) * OUT_HW + (y * SCALE + sy)) * OUT_HW + (x * SCALE + sx)] = a;
        }
    }
}

extern "C" void kernel_launch(void* const* d_in, const int* in_sizes, int n_in,
                              void* d_out, int out_size, void* d_ws, size_t ws_size,
                              hipStream_t stream) {
    const float* X = (const float*)d_in[0];
    const float* lstm_w = (const float*)d_in[1];
    const float* lstm_b = (const float*)d_in[2];
    const float* ow[3] = {(const float*)d_in[3], (const float*)d_in[9], (const float*)d_in[15]};
    const float* ob[3] = {(const float*)d_in[4], (const float*)d_in[10], (const float*)d_in[16]};
    const float* mw[3] = {(const float*)d_in[5], (const float*)d_in[11], (const float*)d_in[17]};
    const float* mb[3] = {(const float*)d_in[6], (const float*)d_in[12], (const float*)d_in[18]};
    const float* dw[3] = {(const float*)d_in[7], (const float*)d_in[13], (const float*)d_in[19]};
    const float* db[3] = {(const float*)d_in[8], (const float*)d_in[14], (const float*)d_in[20]};
    const float* conv_w = (const float*)d_in[21];
    const float* conv_b = (const float*)d_in[22];
    const float* sp_w = (const float*)d_in[23];
    const float* sp_b = (const float*)d_in[24];
    const float* ch_w1 = (const float*)d_in[25];
    const float* ch_b1 = (const float*)d_in[26];
    const float* ch_w2 = (const float*)d_in[27];
    const float* ch_b2 = (const float*)d_in[28];

    float* out = (float*)d_out;
    const size_t OUT_IMG = (size_t)B * NC * OUT_HW * OUT_HW;  // 3145728
    const size_t HIDSZ = (size_t)B * NK * HW;                 // 4194304
    float* hid_out = out + OUT_IMG;
    float* cell_out = out + OUT_IMG + HIDSZ;

    float* ws = (float*)d_ws;
    const size_t XCAT = (size_t)B * CIN * HW;  // 4390912
    float* xcatA = ws;            ws += XCAT;
    float* xcatB = ws;            ws += XCAT;
    float* offb = ws;             ws += (size_t)B * 18 * HW;
    float* maskb = ws;            ws += (size_t)B * 9 * HW;
    float* wT[3];
    for (int i = 0; i < 3; i++) { wT[i] = ws; ws += NK * CIN * K2; }
    float* y3 = ws;               ws += (size_t)B * NC * HW;
    float* pooled = ws;           ws += 16;
    float* chbuf = ws;            ws += (size_t)B * S2 * NC * K2;

    dim3 blk(256);
    dim3 g1(B * HW / 256);        // 256 blocks
    dim3 g4(B * HW / 256, 4);
    dim3 g3(B * HW / 256, 3);
    dim3 gd(B * HW / 64);         // 1024 blocks for tap-split deform

    k_lstm<<<g4, blk, 0, stream>>>(X, lstm_w, lstm_b, xcatA, hid_out, cell_out);
    k_copy_lr<<<g1, blk, 0, stream>>>(X, xcatA, xcatB);
    int ntw = NK * CIN * K2;
    for (int i = 0; i < 3; i++)
        k_transw<<<(ntw + 255) / 256, 256, 0, stream>>>(dw[i], wT[i]);

    // layer 1: xcatA -> xcatB
    k_offmask<<<g3, blk, 0, stream>>>(xcatA, ow[0], ob[0], mw[0], mb[0], offb, maskb);
    k_deform<<<gd, blk, 0, stream>>>(xcatA, offb, maskb, wT[0], db[0], xcatB);
    // layer 2: xcatB -> xcatA
    k_offmask<<<g3, blk, 0, stream>>>(xcatB, ow[1], ob[1], mw[1], mb[1], offb, maskb);
    k_deform<<<gd, blk, 0, stream>>>(xcatB, offb, maskb, wT[1], db[1], xcatA);
    // layer 3: xcatA -> xcatB
    k_offmask<<<g3, blk, 0, stream>>>(xcatA, ow[2], ob[2], mw[2], mb[2], offb, maskb);
    k_deform<<<gd, blk, 0, stream>>>(xcatA, offb, maskb, wT[2], db[2], xcatB);

    k_conv3<<<g3, blk, 0, stream>>>(xcatB, conv_w, conv_b, y3);
    k_pool<<<dim3(B * NC), blk, 0, stream>>>(y3, pooled);
    k_ch<<<dim3(1), dim3(64), 0, stream>>>(pooled, ch_w1, ch_b1, ch_w2, ch_b2, chbuf);
    k_ddf<<<g4, blk, 0, stream>>>(y3, sp_w, sp_b, chbuf, out);
}